// Round 12
// baseline (271.445 us; speedup 1.0000x reference)
//
#include <hip/hip_runtime.h>
#include <hip/hip_fp16.h>
#include <hip/hip_cooperative_groups.h>

namespace cg = cooperative_groups;

#define CHUNK 4096                        // edges per hist/scatter block
#define SEGCAP 6144                       // fine-sort LDS segment capacity

__device__ __forceinline__ unsigned pack_h2(float a, float b) {
    __half2 h = __floats2half2_rn(a, b);
    return *reinterpret_cast<unsigned*>(&h);
}

// ---------------- cooperative: full CSR build + layer-1 GEMV, 3 grid syncs ----------------
// Phase A: per-chunk histogram of col>>8 -> F[bucket*nsb + chunk]
// Phase B: per-bucket exclusive scan of F row (block b = bucket b), bsum[b] = total
// Phase C: staged counting scatter: tmp in destination-bucket order
// Phase D: per-bucket fine sort -> pack/start/dinv + g1 = dinv*(x@W1) fp16
__global__ __launch_bounds__(256) void coop_build(
        const int* __restrict__ col, const int* __restrict__ row,
        const float* __restrict__ ew,
        int* __restrict__ F, int* __restrict__ bsum, int2* __restrict__ tmp,
        unsigned* __restrict__ pack, float* __restrict__ dinv, int* __restrict__ start,
        const float* __restrict__ x, const float* __restrict__ W1,
        __half* __restrict__ g1, int n, int E, int nsb, int nbuck) {
    cg::grid_group grid = cg::this_grid();
    __shared__ int   boff[256];
    __shared__ int   a0[256];             // cnt / sd / fcnt
    __shared__ int   a1[256];             // lofs / foff
    __shared__ int   a2[256];             // cur / fcur
    __shared__ float a3[256];             // off(C, as int) / fdeg(D)
    __shared__ float Ws[1024];            // 4KB W1 (phase D)
    __shared__ char  big[61440];          // C: ed 32K + perm 8K ; D: seg 48K + perm 12K
    int t = threadIdx.x, b = blockIdx.x;

    // ---- Phase A ----
    if (b < nsb) {
        a0[t] = 0;
        __syncthreads();
        int s = b * CHUNK, e = min(E, s + CHUNK);
        for (int i = s + t; i < e; i += 256) atomicAdd(&a0[col[i] >> 8], 1);
        __syncthreads();
        F[t * nsb + b] = a0[t];
    }
    grid.sync();

    // ---- Phase B: block b scans bucket b's row of F (nsb <= 256) ----
    if (b < nbuck) {
        int v = (t < nsb) ? F[b * nsb + t] : 0;
        a0[t] = v;
        __syncthreads();
        for (int o = 1; o < 256; o <<= 1) {
            int x2 = (t >= o) ? a0[t - o] : 0;
            __syncthreads();
            a0[t] += x2;
            __syncthreads();
        }
        if (t < nsb) F[b * nsb + t] = a0[t] - v;
        if (t == 255) bsum[b] = a0[255];
    }
    grid.sync();

    // ---- boff = exclusive scan of bsum (every block, in LDS; persists to phase D) ----
    {
        int v = (t < nbuck) ? bsum[t] : 0;
        boff[t] = v;
        __syncthreads();
        for (int o = 1; o < 256; o <<= 1) {
            int x2 = (t >= o) ? boff[t - o] : 0;
            __syncthreads();
            boff[t] += x2;
            __syncthreads();
        }
        int excl = boff[t] - v;
        __syncthreads();
        boff[t] = excl;
        __syncthreads();
    }

    // ---- Phase C: staged counting scatter of chunk b ----
    if (b < nsb) {
        int* off = (int*)a3;
        off[t] = F[t * nsb + b] + boff[t];
        a0[t] = 0; a2[t] = 0;
        __syncthreads();
        int s = b * CHUNK;
        int m = min(E - s, CHUNK);
        int2* ed = (int2*)big;
        unsigned short* permC = (unsigned short*)(big + sizeof(int2) * CHUNK);
        for (int i = t; i < m; i += 256) {
            int c = col[s + i];
            ed[i] = make_int2((row[s + i] & 0xFFFF) | (c << 16), __float_as_int(ew[s + i]));
            atomicAdd(&a0[c >> 8], 1);
        }
        __syncthreads();
        int v = a0[t];
        a1[t] = v;
        __syncthreads();
        for (int o = 1; o < 256; o <<= 1) {
            int x2 = (t >= o) ? a1[t - o] : 0;
            __syncthreads();
            a1[t] += x2;
            __syncthreads();
        }
        int excl = a1[t] - v;
        __syncthreads();
        a1[t] = excl;
        __syncthreads();
        for (int i = t; i < m; i += 256) {
            int bk = ((unsigned)ed[i].x) >> 24;
            int rk = atomicAdd(&a2[bk], 1);
            permC[a1[bk] + rk] = (unsigned short)i;
        }
        __syncthreads();
        for (int p2 = t; p2 < m; p2 += 256) {       // destination order -> coalesced
            int2 v2 = ed[permC[p2]];
            int bk = ((unsigned)v2.x) >> 24;
            tmp[off[bk] + (p2 - a1[bk])] = v2;
        }
    }
    grid.sync();

    // ---- Phase D: fine sort + dinv/start + fused layer-1 GEMV ----
    Ws[t] = W1[t]; Ws[256 + t] = W1[256 + t];
    Ws[512 + t] = W1[512 + t]; Ws[768 + t] = W1[768 + t];
    if (b >= nbuck) return;
    a0[t] = 0; a3[t] = 0.f; a2[t] = 0;              // fcnt, fdeg, fcur
    __syncthreads();
    int segS = boff[b];
    int segE = (b == nbuck - 1) ? E : boff[b + 1];
    int m = segE - segS;
    int2* seg = (int2*)big;
    unsigned short* permD = (unsigned short*)(big + sizeof(int2) * SEGCAP);
    if (m <= SEGCAP) {
        for (int i = t; i < m; i += 256) seg[i] = tmp[segS + i];
        __syncthreads();
        for (int i = t; i < m; i += 256) {
            int2 v = seg[i];
            int f = (v.x >> 16) & 255;
            atomicAdd(&a0[f], 1);
            atomicAdd(&a3[f], __int_as_float(v.y));
        }
        __syncthreads();
        int val = a0[t];
        a1[t] = val;
        __syncthreads();
        for (int o = 1; o < 256; o <<= 1) {
            int xk = (t >= o) ? a1[t - o] : 0;
            __syncthreads();
            a1[t] += xk;
            __syncthreads();
        }
        int excl = a1[t] - val;
        __syncthreads();
        a1[t] = excl;
        __syncthreads();
        for (int i = t; i < m; i += 256) {
            int f = (seg[i].x >> 16) & 255;
            int rk = atomicAdd(&a2[f], 1);
            permD[a1[f] + rk] = (unsigned short)i;
        }
        __syncthreads();
        for (int p2 = t; p2 < m; p2 += 256) {
            int2 v = seg[permD[p2]];
            __half hw = __float2half_rn(__int_as_float(v.y));
            pack[segS + p2] = (unsigned)(v.x & 0xFFFF) |
                              ((unsigned)*reinterpret_cast<unsigned short*>(&hw) << 16);
        }
    } else {                                         // pathological bucket fallback
        for (int i = segS + t; i < segE; i += 256) {
            int2 v = tmp[i];
            int f = (v.x >> 16) & 255;
            atomicAdd(&a0[f], 1);
            atomicAdd(&a3[f], __int_as_float(v.y));
        }
        __syncthreads();
        int val = a0[t];
        a1[t] = val;
        __syncthreads();
        for (int o = 1; o < 256; o <<= 1) {
            int xk = (t >= o) ? a1[t - o] : 0;
            __syncthreads();
            a1[t] += xk;
            __syncthreads();
        }
        int excl = a1[t] - val;
        __syncthreads();
        a1[t] = excl;
        __syncthreads();
        for (int i = segS + t; i < segE; i += 256) {
            int2 v = tmp[i];
            int f = (v.x >> 16) & 255;
            int rk = atomicAdd(&a2[f], 1);
            __half hw = __float2half_rn(__int_as_float(v.y));
            pack[segS + a1[f] + rk] = (unsigned)(v.x & 0xFFFF) |
                              ((unsigned)*reinterpret_cast<unsigned short*>(&hw) << 16);
        }
    }
    int c = (b << 8) | t;
    float di = rsqrtf(a3[t] + 1.0f);                // + self-loop; deg>=1 always
    if (c < n) {
        dinv[c]  = di;
        start[c] = segS + a1[t];
    }
    if (b == nbuck - 1 && t == 255) start[n] = E;
    // fused layer-1 GEMV: g1[c] = di * (x[c,:16] @ W1), fp16
    if (c >= n) return;
    float xv[16];
    const float4* xr = reinterpret_cast<const float4*>(x + (size_t)c * 16);
#pragma unroll
    for (int i = 0; i < 4; ++i)
        *reinterpret_cast<float4*>(&xv[i * 4]) = xr[i];
    uint2* orow = reinterpret_cast<uint2*>(g1 + ((size_t)c << 6));
    for (int jb = 0; jb < 16; ++jb) {
        float4 acc = make_float4(0.f, 0.f, 0.f, 0.f);
#pragma unroll
        for (int k = 0; k < 16; ++k) {
            float hk = xv[k];
            const float4 wv = *reinterpret_cast<const float4*>(&Ws[k * 64 + jb * 4]);
            acc.x += hk * wv.x; acc.y += hk * wv.y;
            acc.z += hk * wv.z; acc.w += hk * wv.w;
        }
        uint2 st;
        st.x = pack_h2(acc.x * di, acc.y * di);
        st.y = pack_h2(acc.z * di, acc.w * di);
        orow[jb] = st;
    }
}

// ---------------- shared gather body: 4 subs x 4 fp16 ch (8B loads), 8 edges in flight ---
__device__ __forceinline__ float4 load_row4(const __half* __restrict__ g,
                                            unsigned pk, int ch4, float* wout) {
    unsigned short hw = (unsigned short)(pk >> 16);
    *wout = __half2float(*reinterpret_cast<__half*>(&hw));
    uint2 u = *reinterpret_cast<const uint2*>(g + ((size_t)(pk & 0xFFFFu) << 6) + ch4);
    float2 a = __half22float2(*reinterpret_cast<__half2*>(&u.x));
    float2 b = __half22float2(*reinterpret_cast<__half2*>(&u.y));
    return make_float4(a.x, a.y, b.x, b.y);
}

__device__ __forceinline__ float4 gather_acc(const int* __restrict__ start,
                                             const unsigned* __restrict__ pack,
                                             const __half* __restrict__ g,
                                             int wid, int sub, int ch4) {
    int s = start[wid], e = start[wid + 1];
    float4 acc = make_float4(0.f, 0.f, 0.f, 0.f);
    int i = s;
    for (; i + 7 < e; i += 8) {
        unsigned pa = pack[i + sub];
        unsigned pb = pack[i + 4 + sub];
        float wa, wb;
        float4 va = load_row4(g, pa, ch4, &wa);
        float4 vb = load_row4(g, pb, ch4, &wb);
        acc.x += va.x * wa; acc.y += va.y * wa; acc.z += va.z * wa; acc.w += va.w * wa;
        acc.x += vb.x * wb; acc.y += vb.y * wb; acc.z += vb.z * wb; acc.w += vb.w * wb;
    }
    if (i + 3 < e) {
        unsigned pa = pack[i + sub];
        float wa;
        float4 va = load_row4(g, pa, ch4, &wa);
        acc.x += va.x * wa; acc.y += va.y * wa; acc.z += va.z * wa; acc.w += va.w * wa;
        i += 4;
    }
    int rem = e - i;
    if (sub < rem) {
        unsigned pa = pack[i + sub];
        float wa;
        float4 va = load_row4(g, pa, ch4, &wa);
        acc.x += va.x * wa; acc.y += va.y * wa; acc.z += va.z * wa; acc.w += va.w * wa;
    }
#pragma unroll
    for (int m = 16; m <= 32; m <<= 1) {        // butterfly: ALL lanes get full sums
        acc.x += __shfl_xor(acc.x, m, 64);
        acc.y += __shfl_xor(acc.y, m, 64);
        acc.z += __shfl_xor(acc.z, m, 64);
        acc.w += __shfl_xor(acc.w, m, 64);
    }
    return acc;
}

// ---------------- gather (mid) + layer-2 GEMM fused: g2 = di*(relu(...)@W2) fp16 --------
__global__ __launch_bounds__(256) void gather_mid_gemm(const int* __restrict__ start,
                                                       const unsigned* __restrict__ pack,
                                                       const __half* __restrict__ g,
                                                       const float* __restrict__ dinv,
                                                       const float* __restrict__ b1,
                                                       const float* __restrict__ W2,
                                                       __half* __restrict__ g2, int n) {
    __shared__ float Ws[64 * 64];                // 16KB W2
    int t = threadIdx.x;
#pragma unroll
    for (int i = 0; i < 16; ++i) Ws[i * 256 + t] = W2[i * 256 + t];
    __syncthreads();
    int wid = (blockIdx.x * blockDim.x + t) >> 6;
    if (wid >= n) return;
    int lane = t & 63;
    int sub = lane >> 4;
    int ch4 = (lane & 15) << 2;
    float4 acc = gather_acc(start, pack, g, wid, sub, ch4);
    float di = dinv[wid];
    // h row: lanes {q,16+q,32+q,48+q} all hold identical h[4q..4q+3]
    float4 h4;
    {
        uint2 u0 = *reinterpret_cast<const uint2*>(g + ((size_t)wid << 6) + ch4);
        float2 ga = __half22float2(*reinterpret_cast<__half2*>(&u0.x));
        float2 gb = __half22float2(*reinterpret_cast<__half2*>(&u0.y));
        const float4 bb = *reinterpret_cast<const float4*>(b1 + ch4);
        h4.x = fmaxf(di * (acc.x + ga.x) + bb.x, 0.f);
        h4.y = fmaxf(di * (acc.y + ga.y) + bb.y, 0.f);
        h4.z = fmaxf(di * (acc.z + gb.x) + bb.z, 0.f);
        h4.w = fmaxf(di * (acc.w + gb.y) + bb.w, 0.f);
    }
    // GEMV: lane j computes out_j = di * sum_k h[k]*W2[k][j]
    float outj = 0.f;
#pragma unroll
    for (int q = 0; q < 16; ++q) {
        float hx = __shfl(h4.x, q, 64);
        float hy = __shfl(h4.y, q, 64);
        float hz = __shfl(h4.z, q, 64);
        float hw = __shfl(h4.w, q, 64);
        int k = q << 2;
        outj += hx * Ws[k * 64 + lane] + hy * Ws[(k + 1) * 64 + lane] +
                hz * Ws[(k + 2) * 64 + lane] + hw * Ws[(k + 3) * 64 + lane];
    }
    outj *= di;
    float nxt = __shfl_down(outj, 1, 64);
    if (!(lane & 1))                              // 32 lanes write 128B coalesced
        reinterpret_cast<unsigned*>(g2 + ((size_t)wid << 6))[lane >> 1] = pack_h2(outj, nxt);
}

// ---------------- gather (final layer) + head fused: out[c,0:2] ----------------
__global__ __launch_bounds__(256) void gather_head(const int* __restrict__ start,
                                                   const unsigned* __restrict__ pack,
                                                   const __half* __restrict__ g,
                                                   const float* __restrict__ dinv,
                                                   const float* __restrict__ b,
                                                   const float* __restrict__ Wl,
                                                   const float* __restrict__ bl,
                                                   float* __restrict__ out, int n) {
    int wid = (blockIdx.x * blockDim.x + threadIdx.x) >> 6;
    if (wid >= n) return;
    int lane = threadIdx.x & 63;
    int sub = lane >> 4;
    int ch4 = (lane & 15) << 2;
    float4 acc = gather_acc(start, pack, g, wid, sub, ch4);
    if (sub == 0) {
        float di = dinv[wid];
        uint2 u0 = *reinterpret_cast<const uint2*>(g + ((size_t)wid << 6) + ch4);
        float2 ga = __half22float2(*reinterpret_cast<__half2*>(&u0.x));
        float2 gb = __half22float2(*reinterpret_cast<__half2*>(&u0.y));
        const float4 bb = *reinterpret_cast<const float4*>(b + ch4);
        float4 h;
        h.x = fmaxf(di * (acc.x + ga.x) + bb.x, 0.f);
        h.y = fmaxf(di * (acc.y + ga.y) + bb.y, 0.f);
        h.z = fmaxf(di * (acc.z + gb.x) + bb.z, 0.f);
        h.w = fmaxf(di * (acc.w + gb.y) + bb.w, 0.f);
        float s0 = h.x * Wl[(ch4 + 0) * 2] + h.y * Wl[(ch4 + 1) * 2] +
                   h.z * Wl[(ch4 + 2) * 2] + h.w * Wl[(ch4 + 3) * 2];
        float s1 = h.x * Wl[(ch4 + 0) * 2 + 1] + h.y * Wl[(ch4 + 1) * 2 + 1] +
                   h.z * Wl[(ch4 + 2) * 2 + 1] + h.w * Wl[(ch4 + 3) * 2 + 1];
#pragma unroll
        for (int m = 1; m <= 8; m <<= 1) {
            s0 += __shfl_xor(s0, m, 64);
            s1 += __shfl_xor(s1, m, 64);
        }
        if (lane == 0) {
            out[(size_t)wid * 2 + 0] = s0 + bl[0];
            out[(size_t)wid * 2 + 1] = s1 + bl[1];
        }
    }
}

extern "C" void kernel_launch(void* const* d_in, const int* in_sizes, int n_in,
                              void* d_out, int out_size, void* d_ws, size_t ws_size,
                              hipStream_t stream) {
    const float* x  = (const float*)d_in[0];
    const int*   ei = (const int*)d_in[1];
    const float* ew = (const float*)d_in[2];
    const float* W1 = (const float*)d_in[3];
    const float* b1 = (const float*)d_in[4];
    const float* W2 = (const float*)d_in[5];
    const float* b2 = (const float*)d_in[6];
    const float* Wl = (const float*)d_in[7];
    const float* bl = (const float*)d_in[8];
    float* out = (float*)d_out;

    const int N = in_sizes[0] / 16;
    const int E = in_sizes[2];
    const int* row = ei;
    const int* col = ei + E;
    const int nbuck = N >> 8;                    // 256 buckets
    const int nsb   = (E + CHUNK - 1) / CHUNK;   // 256 edge chunks
    const int FSZ   = 256 * nsb;

    // workspace layout:
    //  R0: pack (E*4 = 4MB)                 [coop -> end]
    //  R1: g1 (N*64*2 = 8MB fp16)           [coop tail -> gather_mid_gemm]
    //  R2: 16MB region: {tmp 8MB, F 256KB, bsum 1KB} die at coop end; g2 (8MB) born after
    //  R3: dinv (256KB), start (256KB+4)
    char* p = (char*)d_ws;
    unsigned* pack = (unsigned*)p;  p += (size_t)E * 4;
    __half*   g1   = (__half*)p;    p += (size_t)N * 64 * 2;
    char*     r2   = p;             p += (size_t)N * 64 * 4;
    float*    dinv = (float*)p;     p += (size_t)N * 4;
    int*    startO = (int*)p;       p += (size_t)(N + 1) * 4;

    int2*   tmp  = (int2*)r2;
    int*    F    = (int*)(r2 + (size_t)E * 8);
    int*    bsum = F + FSZ;
    __half* g2   = (__half*)r2;                  // aliases tmp after coop ends

    int grid = (nsb > nbuck) ? nsb : nbuck;      // 256

    void* args[] = {(void*)&col, (void*)&row, (void*)&ew,
                    (void*)&F, (void*)&bsum, (void*)&tmp,
                    (void*)&pack, (void*)&dinv, (void*)&startO,
                    (void*)&x, (void*)&W1, (void*)&g1,
                    (void*)&N, (void*)&E, (void*)&nsb, (void*)&nbuck};
    hipLaunchCooperativeKernel((const void*)coop_build, dim3(grid), dim3(256),
                               args, 0, stream);

    // ---- layer 1 aggregate + relu + layer-2 GEMM -> g2 (fp16) ----
    gather_mid_gemm<<<(N + 3) / 4, 256, 0, stream>>>(startO, pack, g1, dinv, b1, W2, g2, N);

    // ---- layer 2 aggregate + relu + head -> out ----
    gather_head<<<(N + 3) / 4, 256, 0, stream>>>(startO, pack, g2, dinv, b2, Wl, bl, out, N);
}

// Round 13
// 167.974 us; speedup vs baseline: 1.6160x; 1.6160x over previous
//
#include <hip/hip_runtime.h>
#include <hip/hip_fp16.h>

#define CHUNK 4096                        // edges per s1/s3 block
#define SEGCAP 6144                       // s4 LDS segment capacity

__device__ __forceinline__ unsigned pack_h2(float a, float b) {
    __half2 h = __floats2half2_rn(a, b);
    return *reinterpret_cast<unsigned*>(&h);
}

// exclusive-scan bsum[nb<=256] into boff[256] (LDS), all 256 threads participate
__device__ __forceinline__ void scan_boff(const int* __restrict__ bsum, int nb,
                                          int* boff) {
    int t = threadIdx.x;
    int v = (t < nb) ? bsum[t] : 0;
    boff[t] = v;
    __syncthreads();
    for (int o = 1; o < 256; o <<= 1) {
        int x = (t >= o) ? boff[t - o] : 0;
        __syncthreads();
        boff[t] += x;
        __syncthreads();
    }
    int excl = boff[t] - v;
    __syncthreads();
    boff[t] = excl;
    __syncthreads();
}

// ---------------- S1: per-(block,bucket) histogram of col>>8 ----------------
__global__ __launch_bounds__(256) void s1_hist(const int* __restrict__ col,
                                               int* __restrict__ F, int E, int nsb) {
    __shared__ int cnt[256];
    int t = threadIdx.x, b = blockIdx.x;
    cnt[t] = 0;
    __syncthreads();
    int s = b * CHUNK, e = min(E, s + CHUNK);
    for (int i = s + t; i < e; i += 256) atomicAdd(&cnt[col[i] >> 8], 1);   // LDS atomic
    __syncthreads();
    F[t * nsb + b] = cnt[t];              // bucket-major: F[bucket*nsb + block]
}

// ---------------- scanF1: local exclusive scan of F (in place) + bsum ----------------
__global__ void scanF1(int* __restrict__ F, int* __restrict__ bsum, int n) {
    __shared__ int sd[256];
    int t = threadIdx.x, i = blockIdx.x * 256 + t;
    int v = (i < n) ? F[i] : 0;
    sd[t] = v;
    __syncthreads();
    for (int o = 1; o < 256; o <<= 1) {
        int x = (t >= o) ? sd[t - o] : 0;
        __syncthreads();
        sd[t] += x;
        __syncthreads();
    }
    if (i < n) F[i] = sd[t] - v;
    if (t == 255) bsum[blockIdx.x] = sd[255];
}

// ---------------- S3: block-local counting sort -> coalesced scatter to tmp -------------
// tmp[pos] = (row(16b) | c(16b)<<16, ew_fp32). Requires nsb == 256.
__global__ __launch_bounds__(256) void s3_scatter(const int* __restrict__ col,
                                                  const int* __restrict__ row,
                                                  const float* __restrict__ ew,
                                                  const int* __restrict__ F,
                                                  const int* __restrict__ bsum,
                                                  int2* __restrict__ tmp, int E, int nsb) {
    __shared__ int boff[256];
    __shared__ int off[256];
    __shared__ int cnt[256];
    __shared__ int lofs[256];
    __shared__ int cur[256];
    __shared__ int2 ed[CHUNK];                 // 32KB staged edges
    __shared__ unsigned short perm[CHUNK];     // 8KB dest-order permutation
    int t = threadIdx.x, b = blockIdx.x;
    scan_boff(bsum, nsb, boff);                // boff = exclusive scan of block sums
    off[t] = F[t * nsb + b] + boff[t];
    cnt[t] = 0; cur[t] = 0;
    __syncthreads();
    int s = b * CHUNK;
    int m = min(E - s, CHUNK);
    for (int i = t; i < m; i += 256) {         // pass 1: stage + bucket counts
        int c = col[s + i];
        ed[i] = make_int2((row[s + i] & 0xFFFF) | (c << 16), __float_as_int(ew[s + i]));
        atomicAdd(&cnt[c >> 8], 1);
    }
    __syncthreads();
    int v = cnt[t];
    lofs[t] = v;
    __syncthreads();
    for (int o = 1; o < 256; o <<= 1) {
        int x = (t >= o) ? lofs[t - o] : 0;
        __syncthreads();
        lofs[t] += x;
        __syncthreads();
    }
    int excl = lofs[t] - v;
    __syncthreads();
    lofs[t] = excl;
    __syncthreads();
    for (int i = t; i < m; i += 256) {         // pass 2: permutation
        int bk = ((unsigned)ed[i].x) >> 24;
        int rk = atomicAdd(&cur[bk], 1);
        perm[lofs[bk] + rk] = (unsigned short)i;
    }
    __syncthreads();
    for (int p = t; p < m; p += 256) {         // pass 3: destination order -> coalesced
        int2 v2 = ed[perm[p]];
        int bk = ((unsigned)v2.x) >> 24;
        tmp[off[bk] + (p - lofs[bk])] = v2;
    }
}

// ---------------- S4: per-bucket fine sort (LDS-resident) + dinv/start + L1 GEMV --------
__global__ __launch_bounds__(256) void s4_fine(const int2* __restrict__ tmp,
                                               const int* __restrict__ F,
                                               const int* __restrict__ bsum,
                                               unsigned* __restrict__ pack,
                                               float* __restrict__ dinv,
                                               int* __restrict__ start,
                                               const float* __restrict__ x,
                                               const float* __restrict__ W1,
                                               __half* __restrict__ g1,
                                               int n, int E, int nsb, int nbuck) {
    __shared__ int   boff[256];
    __shared__ int   fcnt[256];
    __shared__ float fdeg[256];
    __shared__ int   foff[256];
    __shared__ int   fcur[256];
    __shared__ float Ws[16 * 64];
    __shared__ int2  seg[SEGCAP];              // 48KB
    __shared__ unsigned short perm[SEGCAP];    // 12KB
    int t = threadIdx.x, b = blockIdx.x;
    scan_boff(bsum, nsb, boff);
    reinterpret_cast<float4*>(Ws)[t] = reinterpret_cast<const float4*>(W1)[t];  // 4KB
    fcnt[t] = 0; fdeg[t] = 0.f; fcur[t] = 0;
    __syncthreads();
    int segS = F[b * nsb] + boff[b];
    int segE = (b == nbuck - 1) ? E : (F[(b + 1) * nsb] + boff[b + 1]);
    int m = segE - segS;
    if (m <= SEGCAP) {
        for (int i = t; i < m; i += 256) seg[i] = tmp[segS + i];   // coalesced stage
        __syncthreads();
        for (int i = t; i < m; i += 256) {
            int2 v = seg[i];
            int f = (v.x >> 16) & 255;
            atomicAdd(&fcnt[f], 1);
            atomicAdd(&fdeg[f], __int_as_float(v.y));      // LDS float atomic (fp32)
        }
        __syncthreads();
        int val = fcnt[t];
        foff[t] = val;
        __syncthreads();
        for (int o = 1; o < 256; o <<= 1) {
            int xk = (t >= o) ? foff[t - o] : 0;
            __syncthreads();
            foff[t] += xk;
            __syncthreads();
        }
        int excl = foff[t] - val;
        __syncthreads();
        foff[t] = excl;
        __syncthreads();
        for (int i = t; i < m; i += 256) {                 // permutation
            int f = (seg[i].x >> 16) & 255;
            int rk = atomicAdd(&fcur[f], 1);
            perm[foff[f] + rk] = (unsigned short)i;
        }
        __syncthreads();
        for (int p = t; p < m; p += 256) {                 // coalesced pack write
            int2 v = seg[perm[p]];
            __half hw = __float2half_rn(__int_as_float(v.y));
            pack[segS + p] = (unsigned)(v.x & 0xFFFF) |
                             ((unsigned)*reinterpret_cast<unsigned short*>(&hw) << 16);
        }
    } else {
        // fallback: 2-pass global (pathological bucket)
        for (int i = segS + t; i < segE; i += 256) {
            int2 v = tmp[i];
            int f = (v.x >> 16) & 255;
            atomicAdd(&fcnt[f], 1);
            atomicAdd(&fdeg[f], __int_as_float(v.y));
        }
        __syncthreads();
        int val = fcnt[t];
        foff[t] = val;
        __syncthreads();
        for (int o = 1; o < 256; o <<= 1) {
            int xk = (t >= o) ? foff[t - o] : 0;
            __syncthreads();
            foff[t] += xk;
            __syncthreads();
        }
        int excl = foff[t] - val;
        __syncthreads();
        foff[t] = excl;
        __syncthreads();
        for (int i = segS + t; i < segE; i += 256) {
            int2 v = tmp[i];
            int f = (v.x >> 16) & 255;
            int rk = atomicAdd(&fcur[f], 1);
            __half hw = __float2half_rn(__int_as_float(v.y));
            pack[segS + foff[f] + rk] = (unsigned)(v.x & 0xFFFF) |
                             ((unsigned)*reinterpret_cast<unsigned short*>(&hw) << 16);
        }
    }
    int c = (b << 8) | t;
    float di = rsqrtf(fdeg[t] + 1.0f);              // + self-loop; deg>=1 always
    if (c < n) {
        dinv[c]  = di;
        start[c] = segS + foff[t];
    }
    if (b == nbuck - 1 && t == 255) start[n] = E;
    // ---- fused layer-1 GEMV: g1[c] = di * (x[c,:16] @ W1), fp16 out ----
    if (c >= n) return;
    float xv[16];
    const float4* xr = reinterpret_cast<const float4*>(x + (size_t)c * 16);
#pragma unroll
    for (int i = 0; i < 4; ++i)
        *reinterpret_cast<float4*>(&xv[i * 4]) = xr[i];
    uint2* orow = reinterpret_cast<uint2*>(g1 + ((size_t)c << 6));
    for (int jb = 0; jb < 16; ++jb) {
        float4 acc = make_float4(0.f, 0.f, 0.f, 0.f);
#pragma unroll
        for (int k = 0; k < 16; ++k) {
            float hk = xv[k];
            const float4 wv = *reinterpret_cast<const float4*>(&Ws[k * 64 + jb * 4]);
            acc.x += hk * wv.x; acc.y += hk * wv.y;
            acc.z += hk * wv.z; acc.w += hk * wv.w;
        }
        uint2 st;
        st.x = pack_h2(acc.x * di, acc.y * di);
        st.y = pack_h2(acc.z * di, acc.w * di);
        orow[jb] = st;
    }
}

// ---------------- shared gather body: 4 subs x 4 fp16 ch (8B loads), 8 edges in flight ---
__device__ __forceinline__ float4 load_row4(const __half* __restrict__ g,
                                            unsigned pk, int ch4, float* wout) {
    unsigned short hw = (unsigned short)(pk >> 16);
    *wout = __half2float(*reinterpret_cast<__half*>(&hw));
    uint2 u = *reinterpret_cast<const uint2*>(g + ((size_t)(pk & 0xFFFFu) << 6) + ch4);
    float2 a = __half22float2(*reinterpret_cast<__half2*>(&u.x));
    float2 b = __half22float2(*reinterpret_cast<__half2*>(&u.y));
    return make_float4(a.x, a.y, b.x, b.y);
}

__device__ __forceinline__ float4 gather_acc(const int* __restrict__ start,
                                             const unsigned* __restrict__ pack,
                                             const __half* __restrict__ g,
                                             int wid, int sub, int ch4) {
    int s = start[wid], e = start[wid + 1];
    float4 acc = make_float4(0.f, 0.f, 0.f, 0.f);
    int i = s;
    for (; i + 7 < e; i += 8) {                 // 8 edges in flight per wave
        unsigned pa = pack[i + sub];
        unsigned pb = pack[i + 4 + sub];
        float wa, wb;
        float4 va = load_row4(g, pa, ch4, &wa);
        float4 vb = load_row4(g, pb, ch4, &wb);
        acc.x += va.x * wa; acc.y += va.y * wa; acc.z += va.z * wa; acc.w += va.w * wa;
        acc.x += vb.x * wb; acc.y += vb.y * wb; acc.z += vb.z * wb; acc.w += vb.w * wb;
    }
    if (i + 3 < e) {
        unsigned pa = pack[i + sub];
        float wa;
        float4 va = load_row4(g, pa, ch4, &wa);
        acc.x += va.x * wa; acc.y += va.y * wa; acc.z += va.z * wa; acc.w += va.w * wa;
        i += 4;
    }
    int rem = e - i;
    if (sub < rem) {
        unsigned pa = pack[i + sub];
        float wa;
        float4 va = load_row4(g, pa, ch4, &wa);
        acc.x += va.x * wa; acc.y += va.y * wa; acc.z += va.z * wa; acc.w += va.w * wa;
    }
#pragma unroll
    for (int m = 16; m <= 32; m <<= 1) {        // butterfly: ALL lanes get full sums
        acc.x += __shfl_xor(acc.x, m, 64);
        acc.y += __shfl_xor(acc.y, m, 64);
        acc.z += __shfl_xor(acc.z, m, 64);
        acc.w += __shfl_xor(acc.w, m, 64);
    }
    return acc;
}

// ---------------- gather (mid) + layer-2 GEMM fused: g2 = di*(relu(...)@W2) fp16 --------
__global__ __launch_bounds__(256) void gather_mid_gemm(const int* __restrict__ start,
                                                       const unsigned* __restrict__ pack,
                                                       const __half* __restrict__ g,
                                                       const float* __restrict__ dinv,
                                                       const float* __restrict__ b1,
                                                       const float* __restrict__ W2,
                                                       __half* __restrict__ g2, int n) {
    __shared__ float Ws[64 * 64];                // 16KB W2
    int t = threadIdx.x;
#pragma unroll
    for (int i = 0; i < 16; ++i) Ws[i * 256 + t] = W2[i * 256 + t];
    __syncthreads();
    int wid = (blockIdx.x * blockDim.x + t) >> 6;
    if (wid >= n) return;
    int lane = t & 63;
    int sub = lane >> 4;
    int ch4 = (lane & 15) << 2;
    float4 acc = gather_acc(start, pack, g, wid, sub, ch4);
    float di = dinv[wid];
    // h row: lanes {q,16+q,32+q,48+q} all hold identical h[4q..4q+3]
    float4 h4;
    {
        uint2 u0 = *reinterpret_cast<const uint2*>(g + ((size_t)wid << 6) + ch4);
        float2 ga = __half22float2(*reinterpret_cast<__half2*>(&u0.x));
        float2 gb = __half22float2(*reinterpret_cast<__half2*>(&u0.y));
        const float4 bb = *reinterpret_cast<const float4*>(b1 + ch4);
        h4.x = fmaxf(di * (acc.x + ga.x) + bb.x, 0.f);
        h4.y = fmaxf(di * (acc.y + ga.y) + bb.y, 0.f);
        h4.z = fmaxf(di * (acc.z + gb.x) + bb.z, 0.f);
        h4.w = fmaxf(di * (acc.w + gb.y) + bb.w, 0.f);
    }
    // GEMV: lane j computes out_j = di * sum_k h[k]*W2[k][j]
    float outj = 0.f;
#pragma unroll
    for (int q = 0; q < 16; ++q) {
        float hx = __shfl(h4.x, q, 64);
        float hy = __shfl(h4.y, q, 64);
        float hz = __shfl(h4.z, q, 64);
        float hw = __shfl(h4.w, q, 64);
        int k = q << 2;
        outj += hx * Ws[k * 64 + lane] + hy * Ws[(k + 1) * 64 + lane] +
                hz * Ws[(k + 2) * 64 + lane] + hw * Ws[(k + 3) * 64 + lane];
    }
    outj *= di;
    float nxt = __shfl_down(outj, 1, 64);
    if (!(lane & 1))                              // 32 lanes write 128B coalesced
        reinterpret_cast<unsigned*>(g2 + ((size_t)wid << 6))[lane >> 1] = pack_h2(outj, nxt);
}

// ---------------- gather (final layer) + head fused: out[c,0:2] ----------------
__global__ __launch_bounds__(256) void gather_head(const int* __restrict__ start,
                                                   const unsigned* __restrict__ pack,
                                                   const __half* __restrict__ g,
                                                   const float* __restrict__ dinv,
                                                   const float* __restrict__ b,
                                                   const float* __restrict__ Wl,
                                                   const float* __restrict__ bl,
                                                   float* __restrict__ out, int n) {
    int wid = (blockIdx.x * blockDim.x + threadIdx.x) >> 6;
    if (wid >= n) return;
    int lane = threadIdx.x & 63;
    int sub = lane >> 4;
    int ch4 = (lane & 15) << 2;
    float4 acc = gather_acc(start, pack, g, wid, sub, ch4);
    if (sub == 0) {
        float di = dinv[wid];
        uint2 u0 = *reinterpret_cast<const uint2*>(g + ((size_t)wid << 6) + ch4);
        float2 ga = __half22float2(*reinterpret_cast<__half2*>(&u0.x));
        float2 gb = __half22float2(*reinterpret_cast<__half2*>(&u0.y));
        const float4 bb = *reinterpret_cast<const float4*>(b + ch4);
        float4 h;
        h.x = fmaxf(di * (acc.x + ga.x) + bb.x, 0.f);
        h.y = fmaxf(di * (acc.y + ga.y) + bb.y, 0.f);
        h.z = fmaxf(di * (acc.z + gb.x) + bb.z, 0.f);
        h.w = fmaxf(di * (acc.w + gb.y) + bb.w, 0.f);
        float s0 = h.x * Wl[(ch4 + 0) * 2] + h.y * Wl[(ch4 + 1) * 2] +
                   h.z * Wl[(ch4 + 2) * 2] + h.w * Wl[(ch4 + 3) * 2];
        float s1 = h.x * Wl[(ch4 + 0) * 2 + 1] + h.y * Wl[(ch4 + 1) * 2 + 1] +
                   h.z * Wl[(ch4 + 2) * 2 + 1] + h.w * Wl[(ch4 + 3) * 2 + 1];
#pragma unroll
        for (int m = 1; m <= 8; m <<= 1) {       // reduce across lanes 0..15
            s0 += __shfl_xor(s0, m, 64);
            s1 += __shfl_xor(s1, m, 64);
        }
        if (lane == 0) {
            out[(size_t)wid * 2 + 0] = s0 + bl[0];
            out[(size_t)wid * 2 + 1] = s1 + bl[1];
        }
    }
}

extern "C" void kernel_launch(void* const* d_in, const int* in_sizes, int n_in,
                              void* d_out, int out_size, void* d_ws, size_t ws_size,
                              hipStream_t stream) {
    const float* x  = (const float*)d_in[0];
    const int*   ei = (const int*)d_in[1];
    const float* ew = (const float*)d_in[2];
    const float* W1 = (const float*)d_in[3];
    const float* b1 = (const float*)d_in[4];
    const float* W2 = (const float*)d_in[5];
    const float* b2 = (const float*)d_in[6];
    const float* Wl = (const float*)d_in[7];
    const float* bl = (const float*)d_in[8];
    float* out = (float*)d_out;

    const int N = in_sizes[0] / 16;
    const int E = in_sizes[2];
    const int* row = ei;
    const int* col = ei + E;
    const int nbuck = N >> 8;                    // 256 buckets
    const int nsb   = (E + CHUNK - 1) / CHUNK;   // 256 edge blocks
    const int FSZ   = 256 * nsb;                 // 64K scan entries
    const int FB    = (FSZ + 255) / 256;         // 256 scanF1 blocks

    // workspace layout:
    //  R0: pack (E*4 = 4MB)                 [live: s4 -> end]
    //  R1: g1 (N*64*2 = 8MB fp16)           [live: s4 gemv tail -> gather_mid_gemm]
    //  R2: 16MB region: {tmp 8MB, F 256KB, bsum 1KB} die at s4; g2 (8MB fp16) born after
    //  R3: dinv (256KB), start (256KB+4)
    char* p = (char*)d_ws;
    unsigned* pack = (unsigned*)p;  p += (size_t)E * 4;
    __half*   g1   = (__half*)p;    p += (size_t)N * 64 * 2;
    char*     r2   = p;             p += (size_t)N * 64 * 4;
    float*    dinv = (float*)p;     p += (size_t)N * 4;
    int*    startO = (int*)p;       p += (size_t)(N + 1) * 4;

    int2*   tmp  = (int2*)r2;
    int*    F    = (int*)(r2 + (size_t)E * 8);
    int*    bsum = F + FSZ;
    __half* g2   = (__half*)r2;                  // aliases tmp after s4 ends

    // ---- CSR build via counting sort (no global atomics, coalesced scatters) ----
    s1_hist<<<nsb, 256, 0, stream>>>(col, F, E, nsb);
    scanF1<<<FB, 256, 0, stream>>>(F, bsum, FSZ);
    s3_scatter<<<nsb, 256, 0, stream>>>(col, row, ew, F, bsum, tmp, E, nsb);
    s4_fine<<<nbuck, 256, 0, stream>>>(tmp, F, bsum, pack, dinv, startO,
                                       x, W1, g1, N, E, nsb, nbuck);

    // ---- layer 1 aggregate + relu + layer-2 GEMM -> g2 (fp16) ----
    gather_mid_gemm<<<(N + 3) / 4, 256, 0, stream>>>(startO, pack, g1, dinv, b1, W2, g2, N);

    // ---- layer 2 aggregate + relu + head -> out ----
    gather_head<<<(N + 3) / 4, 256, 0, stream>>>(startO, pack, g2, dinv, b2, Wl, bl, out, N);
}

// Round 14
// 137.426 us; speedup vs baseline: 1.9752x; 1.2223x over previous
//
#include <hip/hip_runtime.h>
#include <hip/hip_fp16.h>

#define CHUNK 4096                        // edges per s1/s3 block
#define SEGCAP 6144                       // s4 LDS segment capacity (mean 4096 + 32 sigma)

__device__ __forceinline__ unsigned pack_h2(float a, float b) {
    __half2 h = __floats2half2_rn(a, b);
    return *reinterpret_cast<unsigned*>(&h);
}

// exclusive-scan bsum[nb<=256] into boff[256] (LDS), all 256 threads participate
__device__ __forceinline__ void scan_boff(const int* __restrict__ bsum, int nb,
                                          int* boff) {
    int t = threadIdx.x;
    int v = (t < nb) ? bsum[t] : 0;
    boff[t] = v;
    __syncthreads();
    for (int o = 1; o < 256; o <<= 1) {
        int x = (t >= o) ? boff[t - o] : 0;
        __syncthreads();
        boff[t] += x;
        __syncthreads();
    }
    int excl = boff[t] - v;
    __syncthreads();
    boff[t] = excl;
    __syncthreads();
}

// ---------------- S1: per-(block,bucket) histogram of col>>8 ----------------
__global__ __launch_bounds__(256) void s1_hist(const int* __restrict__ col,
                                               int* __restrict__ F, int E, int nsb) {
    __shared__ int cnt[256];
    int t = threadIdx.x, b = blockIdx.x;
    cnt[t] = 0;
    __syncthreads();
    int s = b * CHUNK, e = min(E, s + CHUNK);
    for (int i = s + t; i < e; i += 256) atomicAdd(&cnt[col[i] >> 8], 1);   // LDS atomic
    __syncthreads();
    F[t * nsb + b] = cnt[t];              // bucket-major: F[bucket*nsb + block]
}

// ---------------- scanF1: local exclusive scan of F (in place) + bsum ----------------
__global__ void scanF1(int* __restrict__ F, int* __restrict__ bsum, int n) {
    __shared__ int sd[256];
    int t = threadIdx.x, i = blockIdx.x * 256 + t;
    int v = (i < n) ? F[i] : 0;
    sd[t] = v;
    __syncthreads();
    for (int o = 1; o < 256; o <<= 1) {
        int x = (t >= o) ? sd[t - o] : 0;
        __syncthreads();
        sd[t] += x;
        __syncthreads();
    }
    if (i < n) F[i] = sd[t] - v;
    if (t == 255) bsum[blockIdx.x] = sd[255];
}

// ---------------- S3: block-local counting sort -> coalesced scatter to tmp -------------
// tmp[pos] = (row(16b) | c(16b)<<16, ew_fp32). Requires nsb == 256.
__global__ __launch_bounds__(256) void s3_scatter(const int* __restrict__ col,
                                                  const int* __restrict__ row,
                                                  const float* __restrict__ ew,
                                                  const int* __restrict__ F,
                                                  const int* __restrict__ bsum,
                                                  int2* __restrict__ tmp, int E, int nsb) {
    __shared__ int boff[256];
    __shared__ int off[256];
    __shared__ int cnt[256];
    __shared__ int lofs[256];
    __shared__ int cur[256];
    __shared__ int2 ed[CHUNK];                 // 32KB staged edges
    __shared__ unsigned short perm[CHUNK];     // 8KB dest-order permutation
    int t = threadIdx.x, b = blockIdx.x;
    scan_boff(bsum, nsb, boff);                // boff = exclusive scan of block sums
    off[t] = F[t * nsb + b] + boff[t];
    cnt[t] = 0; cur[t] = 0;
    __syncthreads();
    int s = b * CHUNK;
    int m = min(E - s, CHUNK);
    for (int i = t; i < m; i += 256) {         // pass 1: stage + bucket counts
        int c = col[s + i];
        ed[i] = make_int2((row[s + i] & 0xFFFF) | (c << 16), __float_as_int(ew[s + i]));
        atomicAdd(&cnt[c >> 8], 1);
    }
    __syncthreads();
    int v = cnt[t];
    lofs[t] = v;
    __syncthreads();
    for (int o = 1; o < 256; o <<= 1) {
        int x = (t >= o) ? lofs[t - o] : 0;
        __syncthreads();
        lofs[t] += x;
        __syncthreads();
    }
    int excl = lofs[t] - v;
    __syncthreads();
    lofs[t] = excl;
    __syncthreads();
    for (int i = t; i < m; i += 256) {         // pass 2: permutation
        int bk = ((unsigned)ed[i].x) >> 24;
        int rk = atomicAdd(&cur[bk], 1);
        perm[lofs[bk] + rk] = (unsigned short)i;
    }
    __syncthreads();
    for (int p = t; p < m; p += 256) {         // pass 3: destination order -> coalesced
        int2 v2 = ed[perm[p]];
        int bk = ((unsigned)v2.x) >> 24;
        tmp[off[bk] + (p - lofs[bk])] = v2;
    }
}

// ---------------- S4: per-bucket fine sort (LDS-resident) + dinv/start + L1 GEMV --------
__global__ __launch_bounds__(256) void s4_fine(const int2* __restrict__ tmp,
                                               const int* __restrict__ F,
                                               const int* __restrict__ bsum,
                                               unsigned* __restrict__ pack,
                                               float* __restrict__ dinv,
                                               int* __restrict__ start,
                                               const float* __restrict__ x,
                                               const float* __restrict__ W1,
                                               __half* __restrict__ g1,
                                               int n, int E, int nsb, int nbuck) {
    __shared__ int   boff[256];
    __shared__ int   fcnt[256];
    __shared__ float fdeg[256];
    __shared__ int   foff[256];
    __shared__ int   fcur[256];
    __shared__ float Ws[16 * 64];
    __shared__ int2  seg[SEGCAP];              // 48KB
    __shared__ unsigned short perm[SEGCAP];    // 12KB
    int t = threadIdx.x, b = blockIdx.x;
    scan_boff(bsum, nsb, boff);
    reinterpret_cast<float4*>(Ws)[t] = reinterpret_cast<const float4*>(W1)[t];  // 4KB
    fcnt[t] = 0; fdeg[t] = 0.f; fcur[t] = 0;
    __syncthreads();
    int segS = F[b * nsb] + boff[b];
    int segE = (b == nbuck - 1) ? E : (F[(b + 1) * nsb] + boff[b + 1]);
    int m = segE - segS;
    if (m <= SEGCAP) {
        for (int i = t; i < m; i += 256) seg[i] = tmp[segS + i];   // coalesced stage
        __syncthreads();
        for (int i = t; i < m; i += 256) {
            int2 v = seg[i];
            int f = (v.x >> 16) & 255;
            atomicAdd(&fcnt[f], 1);
            atomicAdd(&fdeg[f], __int_as_float(v.y));      // LDS float atomic (fp32)
        }
        __syncthreads();
        int val = fcnt[t];
        foff[t] = val;
        __syncthreads();
        for (int o = 1; o < 256; o <<= 1) {
            int xk = (t >= o) ? foff[t - o] : 0;
            __syncthreads();
            foff[t] += xk;
            __syncthreads();
        }
        int excl = foff[t] - val;
        __syncthreads();
        foff[t] = excl;
        __syncthreads();
        for (int i = t; i < m; i += 256) {                 // permutation
            int f = (seg[i].x >> 16) & 255;
            int rk = atomicAdd(&fcur[f], 1);
            perm[foff[f] + rk] = (unsigned short)i;
        }
        __syncthreads();
        for (int p = t; p < m; p += 256) {                 // coalesced pack write
            int2 v = seg[perm[p]];
            __half hw = __float2half_rn(__int_as_float(v.y));
            pack[segS + p] = (unsigned)(v.x & 0xFFFF) |
                             ((unsigned)*reinterpret_cast<unsigned short*>(&hw) << 16);
        }
    } else {
        // fallback: 2-pass global (pathological bucket)
        for (int i = segS + t; i < segE; i += 256) {
            int2 v = tmp[i];
            int f = (v.x >> 16) & 255;
            atomicAdd(&fcnt[f], 1);
            atomicAdd(&fdeg[f], __int_as_float(v.y));
        }
        __syncthreads();
        int val = fcnt[t];
        foff[t] = val;
        __syncthreads();
        for (int o = 1; o < 256; o <<= 1) {
            int xk = (t >= o) ? foff[t - o] : 0;
            __syncthreads();
            foff[t] += xk;
            __syncthreads();
        }
        int excl = foff[t] - val;
        __syncthreads();
        foff[t] = excl;
        __syncthreads();
        for (int i = segS + t; i < segE; i += 256) {
            int2 v = tmp[i];
            int f = (v.x >> 16) & 255;
            int rk = atomicAdd(&fcur[f], 1);
            __half hw = __float2half_rn(__int_as_float(v.y));
            pack[segS + foff[f] + rk] = (unsigned)(v.x & 0xFFFF) |
                             ((unsigned)*reinterpret_cast<unsigned short*>(&hw) << 16);
        }
    }
    int c = (b << 8) | t;
    float di = rsqrtf(fdeg[t] + 1.0f);              // + self-loop; deg>=1 always
    if (c < n) {
        dinv[c]  = di;
        start[c] = segS + foff[t];
    }
    if (b == nbuck - 1 && t == 255) start[n] = E;
    // ---- fused layer-1 GEMV: g1[c] = di * (x[c,:16] @ W1), fp16 out ----
    if (c >= n) return;
    float xv[16];
    const float4* xr = reinterpret_cast<const float4*>(x + (size_t)c * 16);
#pragma unroll
    for (int i = 0; i < 4; ++i)
        *reinterpret_cast<float4*>(&xv[i * 4]) = xr[i];
    uint2* orow = reinterpret_cast<uint2*>(g1 + ((size_t)c << 6));
    for (int jb = 0; jb < 16; ++jb) {
        float4 acc = make_float4(0.f, 0.f, 0.f, 0.f);
#pragma unroll
        for (int k = 0; k < 16; ++k) {
            float hk = xv[k];
            const float4 wv = *reinterpret_cast<const float4*>(&Ws[k * 64 + jb * 4]);
            acc.x += hk * wv.x; acc.y += hk * wv.y;
            acc.z += hk * wv.z; acc.w += hk * wv.w;
        }
        uint2 st;
        st.x = pack_h2(acc.x * di, acc.y * di);
        st.y = pack_h2(acc.z * di, acc.w * di);
        orow[jb] = st;
    }
}

// ---------------- dense: h[N,64] @ W[64,64] -> g2 = dinv*(h@W2) in fp16 ----------------
__global__ __launch_bounds__(256) void gemm_hid(const float* __restrict__ h,
                                                const float* __restrict__ W,
                                                const float* __restrict__ dinv,
                                                __half* __restrict__ out, int n) {
    __shared__ float Ws[64 * 64];
    int t = threadIdx.x;
#pragma unroll
    for (int i = 0; i < 16; ++i) Ws[i * 256 + t] = W[i * 256 + t];
    __syncthreads();
    int node = blockIdx.x * 256 + t;
    if (node >= n) return;
    float hv[64];
    const float4* hr = reinterpret_cast<const float4*>(h + ((size_t)node << 6));
#pragma unroll
    for (int i = 0; i < 16; ++i)
        *reinterpret_cast<float4*>(&hv[i * 4]) = hr[i];
    float di = dinv[node];
    uint2* orow = reinterpret_cast<uint2*>(out + ((size_t)node << 6));
    for (int jb = 0; jb < 16; ++jb) {
        float4 acc = make_float4(0.f, 0.f, 0.f, 0.f);
#pragma unroll
        for (int k = 0; k < 64; ++k) {
            float hk = hv[k];
            const float4 wv = *reinterpret_cast<const float4*>(&Ws[k * 64 + jb * 4]);
            acc.x += hk * wv.x; acc.y += hk * wv.y;
            acc.z += hk * wv.z; acc.w += hk * wv.w;
        }
        uint2 st;
        st.x = pack_h2(acc.x * di, acc.y * di);
        st.y = pack_h2(acc.z * di, acc.w * di);
        orow[jb] = st;
    }
}

// ---------------- shared gather body: 4 subs x 4 fp16 ch (8B loads), 8 edges in flight ---
__device__ __forceinline__ float4 load_row4(const __half* __restrict__ g,
                                            unsigned pk, int ch4, float* wout) {
    unsigned short hw = (unsigned short)(pk >> 16);
    *wout = __half2float(*reinterpret_cast<__half*>(&hw));
    uint2 u = *reinterpret_cast<const uint2*>(g + ((size_t)(pk & 0xFFFFu) << 6) + ch4);
    float2 a = __half22float2(*reinterpret_cast<__half2*>(&u.x));
    float2 b = __half22float2(*reinterpret_cast<__half2*>(&u.y));
    return make_float4(a.x, a.y, b.x, b.y);
}

__device__ __forceinline__ float4 gather_acc(const int* __restrict__ start,
                                             const unsigned* __restrict__ pack,
                                             const __half* __restrict__ g,
                                             int wid, int sub, int ch4) {
    int s = start[wid], e = start[wid + 1];
    float4 acc = make_float4(0.f, 0.f, 0.f, 0.f);
    int i = s;
    for (; i + 7 < e; i += 8) {                 // 8 edges in flight per wave
        unsigned pa = pack[i + sub];
        unsigned pb = pack[i + 4 + sub];
        float wa, wb;
        float4 va = load_row4(g, pa, ch4, &wa);
        float4 vb = load_row4(g, pb, ch4, &wb);
        acc.x += va.x * wa; acc.y += va.y * wa; acc.z += va.z * wa; acc.w += va.w * wa;
        acc.x += vb.x * wb; acc.y += vb.y * wb; acc.z += vb.z * wb; acc.w += vb.w * wb;
    }
    if (i + 3 < e) {
        unsigned pa = pack[i + sub];
        float wa;
        float4 va = load_row4(g, pa, ch4, &wa);
        acc.x += va.x * wa; acc.y += va.y * wa; acc.z += va.z * wa; acc.w += va.w * wa;
        i += 4;
    }
    int rem = e - i;
    if (sub < rem) {
        unsigned pa = pack[i + sub];
        float wa;
        float4 va = load_row4(g, pa, ch4, &wa);
        acc.x += va.x * wa; acc.y += va.y * wa; acc.z += va.z * wa; acc.w += va.w * wa;
    }
#pragma unroll
    for (int m = 16; m <= 32; m <<= 1) {        // reduce across 4 sub groups
        acc.x += __shfl_xor(acc.x, m, 64);
        acc.y += __shfl_xor(acc.y, m, 64);
        acc.z += __shfl_xor(acc.z, m, 64);
        acc.w += __shfl_xor(acc.w, m, 64);
    }
    return acc;
}

// ---------------- gather (mid layer): h_out = relu(di*(acc + g[c]) + b), fp32 out -------
__global__ __launch_bounds__(256) void gather_mid(const int* __restrict__ start,
                                                  const unsigned* __restrict__ pack,
                                                  const __half* __restrict__ g,
                                                  const float* __restrict__ dinv,
                                                  const float* __restrict__ b,
                                                  float* __restrict__ out, int n) {
    int wid = (blockIdx.x * blockDim.x + threadIdx.x) >> 6;
    if (wid >= n) return;
    int lane = threadIdx.x & 63;
    int sub = lane >> 4;
    int ch4 = (lane & 15) << 2;
    float4 acc = gather_acc(start, pack, g, wid, sub, ch4);
    if (sub == 0) {                              // lanes 0..15 write 256B contiguous
        float di = dinv[wid];
        uint2 u0 = *reinterpret_cast<const uint2*>(g + ((size_t)wid << 6) + ch4);
        float2 ga = __half22float2(*reinterpret_cast<__half2*>(&u0.x));
        float2 gb = __half22float2(*reinterpret_cast<__half2*>(&u0.y));
        const float4 bb = *reinterpret_cast<const float4*>(b + ch4);
        float4 r;
        r.x = fmaxf(di * (acc.x + ga.x) + bb.x, 0.f);
        r.y = fmaxf(di * (acc.y + ga.y) + bb.y, 0.f);
        r.z = fmaxf(di * (acc.z + gb.x) + bb.z, 0.f);
        r.w = fmaxf(di * (acc.w + gb.y) + bb.w, 0.f);
        *reinterpret_cast<float4*>(out + ((size_t)wid << 6) + ch4) = r;
    }
}

// ---------------- gather (final layer) + head fused: out[c,0:2] ----------------
__global__ __launch_bounds__(256) void gather_head(const int* __restrict__ start,
                                                   const unsigned* __restrict__ pack,
                                                   const __half* __restrict__ g,
                                                   const float* __restrict__ dinv,
                                                   const float* __restrict__ b,
                                                   const float* __restrict__ Wl,
                                                   const float* __restrict__ bl,
                                                   float* __restrict__ out, int n) {
    int wid = (blockIdx.x * blockDim.x + threadIdx.x) >> 6;
    if (wid >= n) return;
    int lane = threadIdx.x & 63;
    int sub = lane >> 4;
    int ch4 = (lane & 15) << 2;
    float4 acc = gather_acc(start, pack, g, wid, sub, ch4);
    if (sub == 0) {
        float di = dinv[wid];
        uint2 u0 = *reinterpret_cast<const uint2*>(g + ((size_t)wid << 6) + ch4);
        float2 ga = __half22float2(*reinterpret_cast<__half2*>(&u0.x));
        float2 gb = __half22float2(*reinterpret_cast<__half2*>(&u0.y));
        const float4 bb = *reinterpret_cast<const float4*>(b + ch4);
        float4 h;
        h.x = fmaxf(di * (acc.x + ga.x) + bb.x, 0.f);
        h.y = fmaxf(di * (acc.y + ga.y) + bb.y, 0.f);
        h.z = fmaxf(di * (acc.z + gb.x) + bb.z, 0.f);
        h.w = fmaxf(di * (acc.w + gb.y) + bb.w, 0.f);
        float s0 = h.x * Wl[(ch4 + 0) * 2] + h.y * Wl[(ch4 + 1) * 2] +
                   h.z * Wl[(ch4 + 2) * 2] + h.w * Wl[(ch4 + 3) * 2];
        float s1 = h.x * Wl[(ch4 + 0) * 2 + 1] + h.y * Wl[(ch4 + 1) * 2 + 1] +
                   h.z * Wl[(ch4 + 2) * 2 + 1] + h.w * Wl[(ch4 + 3) * 2 + 1];
#pragma unroll
        for (int m = 1; m <= 8; m <<= 1) {       // reduce across lanes 0..15
            s0 += __shfl_xor(s0, m, 64);
            s1 += __shfl_xor(s1, m, 64);
        }
        if (lane == 0) {
            out[(size_t)wid * 2 + 0] = s0 + bl[0];
            out[(size_t)wid * 2 + 1] = s1 + bl[1];
        }
    }
}

extern "C" void kernel_launch(void* const* d_in, const int* in_sizes, int n_in,
                              void* d_out, int out_size, void* d_ws, size_t ws_size,
                              hipStream_t stream) {
    const float* x  = (const float*)d_in[0];
    const int*   ei = (const int*)d_in[1];
    const float* ew = (const float*)d_in[2];
    const float* W1 = (const float*)d_in[3];
    const float* b1 = (const float*)d_in[4];
    const float* W2 = (const float*)d_in[5];
    const float* b2 = (const float*)d_in[6];
    const float* Wl = (const float*)d_in[7];
    const float* bl = (const float*)d_in[8];
    float* out = (float*)d_out;

    const int N = in_sizes[0] / 16;
    const int E = in_sizes[2];
    const int* row = ei;
    const int* col = ei + E;
    const int NB    = (N + 255) / 256;           // node blocks
    const int nbuck = N >> 8;                    // 256 buckets
    const int nsb   = (E + CHUNK - 1) / CHUNK;   // 256 edge blocks
    const int FSZ   = 256 * nsb;                 // 64K scan entries
    const int FB    = (FSZ + 255) / 256;         // 256 scanF1 blocks

    // workspace layout:
    //  R0: pack (E*4 = 4MB)                 [live: s4 -> end]
    //  R1: bufA = g (N*64*2 = 8MB fp16)     [live: s4 gemv tail -> end]
    //  R2: 16MB region: bufB (h, fp32) ALIASES {tmp 8MB, F 256KB, bsum 1KB}
    //  R3: dinv (256KB), start (256KB+4)
    char* p = (char*)d_ws;
    unsigned* pack = (unsigned*)p;  p += (size_t)E * 4;
    __half*   bufA = (__half*)p;    p += (size_t)N * 64 * 2;
    char*     r2   = p;             p += (size_t)N * 64 * 4;
    float*    dinv = (float*)p;     p += (size_t)N * 4;
    int*    startO = (int*)p;       p += (size_t)(N + 1) * 4;

    int2* tmp  = (int2*)r2;
    int*  F    = (int*)(r2 + (size_t)E * 8);
    int*  bsum = F + FSZ;
    float* bufB = (float*)r2;

    // ---- CSR build via counting sort (no global atomics, coalesced scatters) ----
    s1_hist<<<nsb, 256, 0, stream>>>(col, F, E, nsb);
    scanF1<<<FB, 256, 0, stream>>>(F, bsum, FSZ);
    s3_scatter<<<nsb, 256, 0, stream>>>(col, row, ew, F, bsum, tmp, E, nsb);
    // ---- S4: LDS-resident fine sort + dinv + start + fused layer-1 GEMV (fp16 g1) ----
    s4_fine<<<nbuck, 256, 0, stream>>>(tmp, F, bsum, pack, dinv, startO,
                                       x, W1, bufA, N, E, nsb, nbuck);

    // ---- layer 1 aggregate + relu -> h (fp32) ----
    gather_mid<<<(N + 3) / 4, 256, 0, stream>>>(startO, pack, bufA, dinv, b1, bufB, N);

    // ---- layer 2 GEMM: g2 = dinv*(h@W2) (fp16) ----
    gemm_hid<<<NB, 256, 0, stream>>>(bufB, W2, dinv, bufA, N);

    // ---- layer 2 aggregate + relu + head -> out ----
    gather_head<<<(N + 3) / 4, 256, 0, stream>>>(startO, pack, bufA, dinv, b2, Wl, bl, out, N);
}

// Round 15
// 132.270 us; speedup vs baseline: 2.0522x; 1.0390x over previous
//
#include <hip/hip_runtime.h>
#include <hip/hip_fp16.h>

#define CHUNK 4096                        // edges per s1/s3 block
#define SEGCAP 6144                       // s4 LDS segment capacity (mean 4096 + 32 sigma)

__device__ __forceinline__ unsigned pack_h2(float a, float b) {
    __half2 h = __floats2half2_rn(a, b);
    return *reinterpret_cast<unsigned*>(&h);
}

// exclusive-scan bsum[nb<=256] into boff[256] (LDS), all 256 threads participate
__device__ __forceinline__ void scan_boff(const int* __restrict__ bsum, int nb,
                                          int* boff) {
    int t = threadIdx.x;
    int v = (t < nb) ? bsum[t] : 0;
    boff[t] = v;
    __syncthreads();
    for (int o = 1; o < 256; o <<= 1) {
        int x = (t >= o) ? boff[t - o] : 0;
        __syncthreads();
        boff[t] += x;
        __syncthreads();
    }
    int excl = boff[t] - v;
    __syncthreads();
    boff[t] = excl;
    __syncthreads();
}

// ---------------- S1: per-(block,bucket) histogram of col>>8 ----------------
__global__ __launch_bounds__(256) void s1_hist(const int* __restrict__ col,
                                               int* __restrict__ F, int E, int nsb) {
    __shared__ int cnt[256];
    int t = threadIdx.x, b = blockIdx.x;
    cnt[t] = 0;
    __syncthreads();
    int s = b * CHUNK, e = min(E, s + CHUNK);
    for (int i = s + t; i < e; i += 256) atomicAdd(&cnt[col[i] >> 8], 1);   // LDS atomic
    __syncthreads();
    F[t * nsb + b] = cnt[t];              // bucket-major: F[bucket*nsb + block]
}

// ---------------- scanF1: local exclusive scan of F (in place) + bsum ----------------
__global__ void scanF1(int* __restrict__ F, int* __restrict__ bsum, int n) {
    __shared__ int sd[256];
    int t = threadIdx.x, i = blockIdx.x * 256 + t;
    int v = (i < n) ? F[i] : 0;
    sd[t] = v;
    __syncthreads();
    for (int o = 1; o < 256; o <<= 1) {
        int x = (t >= o) ? sd[t - o] : 0;
        __syncthreads();
        sd[t] += x;
        __syncthreads();
    }
    if (i < n) F[i] = sd[t] - v;
    if (t == 255) bsum[blockIdx.x] = sd[255];
}

// ---------------- S3: block-local counting sort -> coalesced scatter to tmp -------------
// tmp[pos] = (row(16b) | c(16b)<<16, ew_fp32). Requires nsb == 256.
__global__ __launch_bounds__(256) void s3_scatter(const int* __restrict__ col,
                                                  const int* __restrict__ row,
                                                  const float* __restrict__ ew,
                                                  const int* __restrict__ F,
                                                  const int* __restrict__ bsum,
                                                  int2* __restrict__ tmp, int E, int nsb) {
    __shared__ int boff[256];
    __shared__ int off[256];
    __shared__ int cnt[256];
    __shared__ int lofs[256];
    __shared__ int cur[256];
    __shared__ int2 ed[CHUNK];                 // 32KB staged edges
    __shared__ unsigned short perm[CHUNK];     // 8KB dest-order permutation
    int t = threadIdx.x, b = blockIdx.x;
    scan_boff(bsum, nsb, boff);                // boff = exclusive scan of block sums
    off[t] = F[t * nsb + b] + boff[t];
    cnt[t] = 0; cur[t] = 0;
    __syncthreads();
    int s = b * CHUNK;
    int m = min(E - s, CHUNK);
    for (int i = t; i < m; i += 256) {         // pass 1: stage + bucket counts
        int c = col[s + i];
        ed[i] = make_int2((row[s + i] & 0xFFFF) | (c << 16), __float_as_int(ew[s + i]));
        atomicAdd(&cnt[c >> 8], 1);
    }
    __syncthreads();
    int v = cnt[t];
    lofs[t] = v;
    __syncthreads();
    for (int o = 1; o < 256; o <<= 1) {
        int x = (t >= o) ? lofs[t - o] : 0;
        __syncthreads();
        lofs[t] += x;
        __syncthreads();
    }
    int excl = lofs[t] - v;
    __syncthreads();
    lofs[t] = excl;
    __syncthreads();
    for (int i = t; i < m; i += 256) {         // pass 2: permutation
        int bk = ((unsigned)ed[i].x) >> 24;
        int rk = atomicAdd(&cur[bk], 1);
        perm[lofs[bk] + rk] = (unsigned short)i;
    }
    __syncthreads();
    for (int p = t; p < m; p += 256) {         // pass 3: destination order -> coalesced
        int2 v2 = ed[perm[p]];
        int bk = ((unsigned)v2.x) >> 24;
        tmp[off[bk] + (p - lofs[bk])] = v2;
    }
}

// ---------------- S4: per-bucket fine sort (LDS-resident) + dinv/start + L1 GEMV --------
__global__ __launch_bounds__(256) void s4_fine(const int2* __restrict__ tmp,
                                               const int* __restrict__ F,
                                               const int* __restrict__ bsum,
                                               unsigned* __restrict__ pack,
                                               float* __restrict__ dinv,
                                               int* __restrict__ start,
                                               const float* __restrict__ x,
                                               const float* __restrict__ W1,
                                               __half* __restrict__ g1,
                                               int n, int E, int nsb, int nbuck) {
    __shared__ int   boff[256];
    __shared__ int   fcnt[256];
    __shared__ float fdeg[256];
    __shared__ int   foff[256];
    __shared__ int   fcur[256];
    __shared__ float Ws[16 * 64];
    __shared__ int2  seg[SEGCAP];              // 48KB
    __shared__ unsigned short perm[SEGCAP];    // 12KB
    int t = threadIdx.x, b = blockIdx.x;
    scan_boff(bsum, nsb, boff);
    reinterpret_cast<float4*>(Ws)[t] = reinterpret_cast<const float4*>(W1)[t];  // 4KB
    fcnt[t] = 0; fdeg[t] = 0.f; fcur[t] = 0;
    __syncthreads();
    int segS = F[b * nsb] + boff[b];
    int segE = (b == nbuck - 1) ? E : (F[(b + 1) * nsb] + boff[b + 1]);
    int m = segE - segS;
    if (m <= SEGCAP) {
        for (int i = t; i < m; i += 256) seg[i] = tmp[segS + i];   // coalesced stage
        __syncthreads();
        for (int i = t; i < m; i += 256) {
            int2 v = seg[i];
            int f = (v.x >> 16) & 255;
            atomicAdd(&fcnt[f], 1);
            atomicAdd(&fdeg[f], __int_as_float(v.y));      // LDS float atomic (fp32)
        }
        __syncthreads();
        int val = fcnt[t];
        foff[t] = val;
        __syncthreads();
        for (int o = 1; o < 256; o <<= 1) {
            int xk = (t >= o) ? foff[t - o] : 0;
            __syncthreads();
            foff[t] += xk;
            __syncthreads();
        }
        int excl = foff[t] - val;
        __syncthreads();
        foff[t] = excl;
        __syncthreads();
        for (int i = t; i < m; i += 256) {                 // permutation
            int f = (seg[i].x >> 16) & 255;
            int rk = atomicAdd(&fcur[f], 1);
            perm[foff[f] + rk] = (unsigned short)i;
        }
        __syncthreads();
        for (int p = t; p < m; p += 256) {                 // coalesced pack write
            int2 v = seg[perm[p]];
            __half hw = __float2half_rn(__int_as_float(v.y));
            pack[segS + p] = (unsigned)(v.x & 0xFFFF) |
                             ((unsigned)*reinterpret_cast<unsigned short*>(&hw) << 16);
        }
    } else {
        // fallback: 2-pass global (pathological bucket)
        for (int i = segS + t; i < segE; i += 256) {
            int2 v = tmp[i];
            int f = (v.x >> 16) & 255;
            atomicAdd(&fcnt[f], 1);
            atomicAdd(&fdeg[f], __int_as_float(v.y));
        }
        __syncthreads();
        int val = fcnt[t];
        foff[t] = val;
        __syncthreads();
        for (int o = 1; o < 256; o <<= 1) {
            int xk = (t >= o) ? foff[t - o] : 0;
            __syncthreads();
            foff[t] += xk;
            __syncthreads();
        }
        int excl = foff[t] - val;
        __syncthreads();
        foff[t] = excl;
        __syncthreads();
        for (int i = segS + t; i < segE; i += 256) {
            int2 v = tmp[i];
            int f = (v.x >> 16) & 255;
            int rk = atomicAdd(&fcur[f], 1);
            __half hw = __float2half_rn(__int_as_float(v.y));
            pack[segS + foff[f] + rk] = (unsigned)(v.x & 0xFFFF) |
                             ((unsigned)*reinterpret_cast<unsigned short*>(&hw) << 16);
        }
    }
    int c = (b << 8) | t;
    float di = rsqrtf(fdeg[t] + 1.0f);              // + self-loop; deg>=1 always
    if (c < n) {
        dinv[c]  = di;
        start[c] = segS + foff[t];
    }
    if (b == nbuck - 1 && t == 255) start[n] = E;
    // ---- fused layer-1 GEMV: g1[c] = di * (x[c,:16] @ W1), fp16 out ----
    if (c >= n) return;
    float xv[16];
    const float4* xr = reinterpret_cast<const float4*>(x + (size_t)c * 16);
#pragma unroll
    for (int i = 0; i < 4; ++i)
        *reinterpret_cast<float4*>(&xv[i * 4]) = xr[i];
    uint2* orow = reinterpret_cast<uint2*>(g1 + ((size_t)c << 6));
    for (int jb = 0; jb < 16; ++jb) {
        float4 acc = make_float4(0.f, 0.f, 0.f, 0.f);
#pragma unroll
        for (int k = 0; k < 16; ++k) {
            float hk = xv[k];
            const float4 wv = *reinterpret_cast<const float4*>(&Ws[k * 64 + jb * 4]);
            acc.x += hk * wv.x; acc.y += hk * wv.y;
            acc.z += hk * wv.z; acc.w += hk * wv.w;
        }
        uint2 st;
        st.x = pack_h2(acc.x * di, acc.y * di);
        st.y = pack_h2(acc.z * di, acc.w * di);
        orow[jb] = st;
    }
}

// ---------------- dense: h[N,64] @ W[64,64] -> g2 = dinv*(h@W2) in fp16 ----------------
__global__ __launch_bounds__(256) void gemm_hid(const float* __restrict__ h,
                                                const float* __restrict__ W,
                                                const float* __restrict__ dinv,
                                                __half* __restrict__ out, int n) {
    __shared__ float Ws[64 * 64];
    int t = threadIdx.x;
#pragma unroll
    for (int i = 0; i < 16; ++i) Ws[i * 256 + t] = W[i * 256 + t];
    __syncthreads();
    int node = blockIdx.x * 256 + t;
    if (node >= n) return;
    float hv[64];
    const float4* hr = reinterpret_cast<const float4*>(h + ((size_t)node << 6));
#pragma unroll
    for (int i = 0; i < 16; ++i)
        *reinterpret_cast<float4*>(&hv[i * 4]) = hr[i];
    float di = dinv[node];
    uint2* orow = reinterpret_cast<uint2*>(out + ((size_t)node << 6));
    for (int jb = 0; jb < 16; ++jb) {
        float4 acc = make_float4(0.f, 0.f, 0.f, 0.f);
#pragma unroll
        for (int k = 0; k < 64; ++k) {
            float hk = hv[k];
            const float4 wv = *reinterpret_cast<const float4*>(&Ws[k * 64 + jb * 4]);
            acc.x += hk * wv.x; acc.y += hk * wv.y;
            acc.z += hk * wv.z; acc.w += hk * wv.w;
        }
        uint2 st;
        st.x = pack_h2(acc.x * di, acc.y * di);
        st.y = pack_h2(acc.z * di, acc.w * di);
        orow[jb] = st;
    }
}

// ---------------- shared gather body: 4 subs x 4 fp16 ch (8B loads), 16 edges in flight --
__device__ __forceinline__ float4 load_row4(const __half* __restrict__ g,
                                            unsigned pk, int ch4, float* wout) {
    unsigned short hw = (unsigned short)(pk >> 16);
    *wout = __half2float(*reinterpret_cast<__half*>(&hw));
    uint2 u = *reinterpret_cast<const uint2*>(g + ((size_t)(pk & 0xFFFFu) << 6) + ch4);
    float2 a = __half22float2(*reinterpret_cast<__half2*>(&u.x));
    float2 b = __half22float2(*reinterpret_cast<__half2*>(&u.y));
    return make_float4(a.x, a.y, b.x, b.y);
}

__device__ __forceinline__ float4 gather_acc(const int* __restrict__ start,
                                             const unsigned* __restrict__ pack,
                                             const __half* __restrict__ g,
                                             int wid, int sub, int ch4) {
    int s = start[wid], e = start[wid + 1];
    float4 acc = make_float4(0.f, 0.f, 0.f, 0.f);
    int i = s;
    for (; i + 15 < e; i += 16) {               // 16 edges in flight per wave
        unsigned p0 = pack[i + sub];
        unsigned p1 = pack[i + 4 + sub];
        unsigned p2 = pack[i + 8 + sub];
        unsigned p3 = pack[i + 12 + sub];
        float w0, w1, w2, w3;
        float4 v0 = load_row4(g, p0, ch4, &w0);
        float4 v1 = load_row4(g, p1, ch4, &w1);
        float4 v2 = load_row4(g, p2, ch4, &w2);
        float4 v3 = load_row4(g, p3, ch4, &w3);
        acc.x += v0.x * w0; acc.y += v0.y * w0; acc.z += v0.z * w0; acc.w += v0.w * w0;
        acc.x += v1.x * w1; acc.y += v1.y * w1; acc.z += v1.z * w1; acc.w += v1.w * w1;
        acc.x += v2.x * w2; acc.y += v2.y * w2; acc.z += v2.z * w2; acc.w += v2.w * w2;
        acc.x += v3.x * w3; acc.y += v3.y * w3; acc.z += v3.z * w3; acc.w += v3.w * w3;
    }
    if (i + 7 < e) {                            // >= 8 remain
        unsigned p0 = pack[i + sub];
        unsigned p1 = pack[i + 4 + sub];
        float w0, w1;
        float4 v0 = load_row4(g, p0, ch4, &w0);
        float4 v1 = load_row4(g, p1, ch4, &w1);
        acc.x += v0.x * w0; acc.y += v0.y * w0; acc.z += v0.z * w0; acc.w += v0.w * w0;
        acc.x += v1.x * w1; acc.y += v1.y * w1; acc.z += v1.z * w1; acc.w += v1.w * w1;
        i += 8;
    }
    if (i + 3 < e) {                            // >= 4 remain
        unsigned p0 = pack[i + sub];
        float w0;
        float4 v0 = load_row4(g, p0, ch4, &w0);
        acc.x += v0.x * w0; acc.y += v0.y * w0; acc.z += v0.z * w0; acc.w += v0.w * w0;
        i += 4;
    }
    int rem = e - i;                            // 0..3
    if (sub < rem) {
        unsigned p0 = pack[i + sub];
        float w0;
        float4 v0 = load_row4(g, p0, ch4, &w0);
        acc.x += v0.x * w0; acc.y += v0.y * w0; acc.z += v0.z * w0; acc.w += v0.w * w0;
    }
#pragma unroll
    for (int m = 16; m <= 32; m <<= 1) {        // reduce across 4 sub groups
        acc.x += __shfl_xor(acc.x, m, 64);
        acc.y += __shfl_xor(acc.y, m, 64);
        acc.z += __shfl_xor(acc.z, m, 64);
        acc.w += __shfl_xor(acc.w, m, 64);
    }
    return acc;
}

// ---------------- gather (mid layer): h_out = relu(di*(acc + g[c]) + b), fp32 out -------
__global__ __launch_bounds__(256) void gather_mid(const int* __restrict__ start,
                                                  const unsigned* __restrict__ pack,
                                                  const __half* __restrict__ g,
                                                  const float* __restrict__ dinv,
                                                  const float* __restrict__ b,
                                                  float* __restrict__ out, int n) {
    int wid = (blockIdx.x * blockDim.x + threadIdx.x) >> 6;
    if (wid >= n) return;
    int lane = threadIdx.x & 63;
    int sub = lane >> 4;
    int ch4 = (lane & 15) << 2;
    float4 acc = gather_acc(start, pack, g, wid, sub, ch4);
    if (sub == 0) {                              // lanes 0..15 write 256B contiguous
        float di = dinv[wid];
        uint2 u0 = *reinterpret_cast<const uint2*>(g + ((size_t)wid << 6) + ch4);
        float2 ga = __half22float2(*reinterpret_cast<__half2*>(&u0.x));
        float2 gb = __half22float2(*reinterpret_cast<__half2*>(&u0.y));
        const float4 bb = *reinterpret_cast<const float4*>(b + ch4);
        float4 r;
        r.x = fmaxf(di * (acc.x + ga.x) + bb.x, 0.f);
        r.y = fmaxf(di * (acc.y + ga.y) + bb.y, 0.f);
        r.z = fmaxf(di * (acc.z + gb.x) + bb.z, 0.f);
        r.w = fmaxf(di * (acc.w + gb.y) + bb.w, 0.f);
        *reinterpret_cast<float4*>(out + ((size_t)wid << 6) + ch4) = r;
    }
}

// ---------------- gather (final layer) + head fused: out[c,0:2] ----------------
__global__ __launch_bounds__(256) void gather_head(const int* __restrict__ start,
                                                   const unsigned* __restrict__ pack,
                                                   const __half* __restrict__ g,
                                                   const float* __restrict__ dinv,
                                                   const float* __restrict__ b,
                                                   const float* __restrict__ Wl,
                                                   const float* __restrict__ bl,
                                                   float* __restrict__ out, int n) {
    int wid = (blockIdx.x * blockDim.x + threadIdx.x) >> 6;
    if (wid >= n) return;
    int lane = threadIdx.x & 63;
    int sub = lane >> 4;
    int ch4 = (lane & 15) << 2;
    float4 acc = gather_acc(start, pack, g, wid, sub, ch4);
    if (sub == 0) {
        float di = dinv[wid];
        uint2 u0 = *reinterpret_cast<const uint2*>(g + ((size_t)wid << 6) + ch4);
        float2 ga = __half22float2(*reinterpret_cast<__half2*>(&u0.x));
        float2 gb = __half22float2(*reinterpret_cast<__half2*>(&u0.y));
        const float4 bb = *reinterpret_cast<const float4*>(b + ch4);
        float4 h;
        h.x = fmaxf(di * (acc.x + ga.x) + bb.x, 0.f);
        h.y = fmaxf(di * (acc.y + ga.y) + bb.y, 0.f);
        h.z = fmaxf(di * (acc.z + gb.x) + bb.z, 0.f);
        h.w = fmaxf(di * (acc.w + gb.y) + bb.w, 0.f);
        float s0 = h.x * Wl[(ch4 + 0) * 2] + h.y * Wl[(ch4 + 1) * 2] +
                   h.z * Wl[(ch4 + 2) * 2] + h.w * Wl[(ch4 + 3) * 2];
        float s1 = h.x * Wl[(ch4 + 0) * 2 + 1] + h.y * Wl[(ch4 + 1) * 2 + 1] +
                   h.z * Wl[(ch4 + 2) * 2 + 1] + h.w * Wl[(ch4 + 3) * 2 + 1];
#pragma unroll
        for (int m = 1; m <= 8; m <<= 1) {       // reduce across lanes 0..15
            s0 += __shfl_xor(s0, m, 64);
            s1 += __shfl_xor(s1, m, 64);
        }
        if (lane == 0) {
            out[(size_t)wid * 2 + 0] = s0 + bl[0];
            out[(size_t)wid * 2 + 1] = s1 + bl[1];
        }
    }
}

extern "C" void kernel_launch(void* const* d_in, const int* in_sizes, int n_in,
                              void* d_out, int out_size, void* d_ws, size_t ws_size,
                              hipStream_t stream) {
    const float* x  = (const float*)d_in[0];
    const int*   ei = (const int*)d_in[1];
    const float* ew = (const float*)d_in[2];
    const float* W1 = (const float*)d_in[3];
    const float* b1 = (const float*)d_in[4];
    const float* W2 = (const float*)d_in[5];
    const float* b2 = (const float*)d_in[6];
    const float* Wl = (const float*)d_in[7];
    const float* bl = (const float*)d_in[8];
    float* out = (float*)d_out;

    const int N = in_sizes[0] / 16;
    const int E = in_sizes[2];
    const int* row = ei;
    const int* col = ei + E;
    const int NB    = (N + 255) / 256;           // node blocks
    const int nbuck = N >> 8;                    // 256 buckets
    const int nsb   = (E + CHUNK - 1) / CHUNK;   // 256 edge blocks
    const int FSZ   = 256 * nsb;                 // 64K scan entries
    const int FB    = (FSZ + 255) / 256;         // 256 scanF1 blocks

    // workspace layout:
    //  R0: pack (E*4 = 4MB)                 [live: s4 -> end]
    //  R1: bufA = g (N*64*2 = 8MB fp16)     [live: s4 gemv tail -> end]
    //  R2: 16MB region: bufB (h, fp32) ALIASES {tmp 8MB, F 256KB, bsum 1KB}
    //  R3: dinv (256KB), start (256KB+4)
    char* p = (char*)d_ws;
    unsigned* pack = (unsigned*)p;  p += (size_t)E * 4;
    __half*   bufA = (__half*)p;    p += (size_t)N * 64 * 2;
    char*     r2   = p;             p += (size_t)N * 64 * 4;
    float*    dinv = (float*)p;     p += (size_t)N * 4;
    int*    startO = (int*)p;       p += (size_t)(N + 1) * 4;

    int2* tmp  = (int2*)r2;
    int*  F    = (int*)(r2 + (size_t)E * 8);
    int*  bsum = F + FSZ;
    float* bufB = (float*)r2;

    // ---- CSR build via counting sort (no global atomics, coalesced scatters) ----
    s1_hist<<<nsb, 256, 0, stream>>>(col, F, E, nsb);
    scanF1<<<FB, 256, 0, stream>>>(F, bsum, FSZ);
    s3_scatter<<<nsb, 256, 0, stream>>>(col, row, ew, F, bsum, tmp, E, nsb);
    // ---- S4: LDS-resident fine sort + dinv + start + fused layer-1 GEMV (fp16 g1) ----
    s4_fine<<<nbuck, 256, 0, stream>>>(tmp, F, bsum, pack, dinv, startO,
                                       x, W1, bufA, N, E, nsb, nbuck);

    // ---- layer 1 aggregate + relu -> h (fp32) ----
    gather_mid<<<(N + 3) / 4, 256, 0, stream>>>(startO, pack, bufA, dinv, b1, bufB, N);

    // ---- layer 2 GEMM: g2 = dinv*(h@W2) (fp16) ----
    gemm_hid<<<NB, 256, 0, stream>>>(bufB, W2, dinv, bufA, N);

    // ---- layer 2 aggregate + relu + head -> out ----
    gather_head<<<(N + 3) / 4, 256, 0, stream>>>(startO, pack, bufA, dinv, b2, Wl, bl, out, N);
}